// Round 6
// baseline (236.238 us; speedup 1.0000x reference)
//
#include <hip/hip_runtime.h>
#include <cstdint>

#define S_REAL 1992
#define S_PAD  2048
#define DIMSZ  2048
#define NHEAD  16
#define DHD    128

typedef float f32x4 __attribute__((ext_vector_type(4)));
typedef float f32x16 __attribute__((ext_vector_type(16)));
typedef __bf16 bf16x8 __attribute__((ext_vector_type(8)));
typedef unsigned short u16x8 __attribute__((ext_vector_type(8)));

__device__ __forceinline__ unsigned short f2bf(float f){
  uint32_t u = __float_as_uint(f);
  u += 0x7fffu + ((u >> 16) & 1u);
  return (unsigned short)(u >> 16);
}

__device__ __forceinline__ void gload16(const void* g, void* l){
  __builtin_amdgcn_global_load_lds(
      (const __attribute__((address_space(1))) uint32_t*)g,
      (__attribute__((address_space(3))) uint32_t*)l,
      16, 0, 0);
}

template<int N> __device__ __forceinline__ void waitbar(){
  if constexpr (N == 8)      asm volatile("s_waitcnt vmcnt(8)\n\ts_barrier" ::: "memory");
  else if constexpr (N == 6) asm volatile("s_waitcnt vmcnt(6)\n\ts_barrier" ::: "memory");
  else if constexpr (N == 4) asm volatile("s_waitcnt vmcnt(4)\n\ts_barrier" ::: "memory");
  else if constexpr (N == 3) asm volatile("s_waitcnt vmcnt(3)\n\ts_barrier" ::: "memory");
  else if constexpr (N == 2) asm volatile("s_waitcnt vmcnt(2)\n\ts_barrier" ::: "memory");
  else                       asm volatile("s_waitcnt vmcnt(0)\n\ts_barrier" ::: "memory");
}

// ---------------- fused fp32 -> bf16 convert: X + 4 weights in one launch ----------
__launch_bounds__(256)
__global__ void k_cvt5(const float* __restrict__ s0, const float* __restrict__ s1,
                       const float* __restrict__ s2, const float* __restrict__ s3,
                       const float* __restrict__ s4,
                       unsigned short* __restrict__ d0, unsigned short* __restrict__ d1,
                       unsigned short* __restrict__ d2, unsigned short* __restrict__ d3,
                       unsigned short* __restrict__ d4,
                       int nX, int nW)
{
  int i = blockIdx.x * 256 + threadIdx.x;
  const float* s; unsigned short* d; int j;
  if (i < nX){ s = s0; d = d0; j = i; }
  else {
    int k = i - nX;
    int wsel = k / nW; j = k - wsel * nW;
    s = (wsel == 0) ? s1 : (wsel == 1) ? s2 : (wsel == 2) ? s3 : s4;
    d = (wsel == 0) ? d1 : (wsel == 1) ? d2 : (wsel == 2) ? d3 : d4;
  }
  const float4* sp = (const float4*)s + (size_t)j * 2;
  float4 a = sp[0], b = sp[1];
  u16x8 o;
  o[0]=f2bf(a.x); o[1]=f2bf(a.y); o[2]=f2bf(a.z); o[3]=f2bf(a.w);
  o[4]=f2bf(b.x); o[5]=f2bf(b.y); o[6]=f2bf(b.z); o[7]=f2bf(b.w);
  *((u16x8*)d + j) = o;
}

// ---------------- 256x256 phase-split GEMM (QKV) ------------------------------------
// 8 waves (2M x 4N, wave tile 128x64 = 4x2 32-blocks), BK=32, 4 LDS buffers (128 KB),
// stage-ahead-3, counted vmcnt(8) once per K-tile (never 0 in the main loop).
// Per tile: 2 phases, each {ds_read frags || stage 2 chunks of t+3 -> s_barrier ->
// setprio(1) 8xMFMA setprio(0) -> s_barrier}. B-frags read in phase 0 are reused in
// phase 1 from registers.
// Race-safety: STAGE(t+3) writes buf[(t+3)&3] = buf[(t-1)&3]; its last readers were
// tile t-1's phases, all complete before tile t's first barrier (program order for
// own wave + barrier for others). vmcnt(8) at tile-t end allows t+2,t+3 (8 loads)
// outstanding and guarantees t+1's loads (issued ~6 phases earlier) retired.
// Swizzle: logical k-chunk c stored at physical slot c^(row&3); inverse applied on
// the per-lane GLOBAL source so the DMA dest stays linear (both-sides rule).
__launch_bounds__(512, 2)
__global__ void k_g256(const unsigned short* __restrict__ A,
                       const unsigned short* __restrict__ B0,
                       const unsigned short* __restrict__ B1,
                       const unsigned short* __restrict__ B2,
                       const float* __restrict__ bias0,
                       const float* __restrict__ bias1,
                       const float* __restrict__ bias2,
                       float* __restrict__ C0, float* __restrict__ C1, float* __restrict__ C2,
                       int Mreal)
{
  constexpr int BUFE = 16384;         // 32 KB per buffer (A 256x32 + B 256x32)
  constexpr int NT   = DIMSZ / 32;    // 64 K-tiles
  __shared__ unsigned short lds[4 * BUFE];

  const unsigned short* Bm = (blockIdx.z == 0) ? B0 : ((blockIdx.z == 1) ? B1 : B2);
  const float* bias        = (blockIdx.z == 0) ? bias0 : ((blockIdx.z == 1) ? bias1 : bias2);
  float* C                 = (blockIdx.z == 0) ? C0 : ((blockIdx.z == 1) ? C1 : C2);

  // XCD-chunked bijective swizzle over the 64 (x,y) blocks: each XCD owns one
  // m-panel (1 MB, L2-pinned) and streams the 8 n-panels.
  const int fid = blockIdx.x + (blockIdx.y << 3);
  const int nf  = (fid & 7) * 8 + (fid >> 3);
  const int m0  = (nf >> 3) * 256, n0 = (nf & 7) * 256;

  const int tid = threadIdx.x;
  const int w = tid >> 6, l = tid & 63;
  const int l31 = l & 31, l5 = l >> 5;
  const int wrv = (w >> 2) * 128;     // wave M base (0 / 128)
  const int wcv = (w & 3) * 64;       // wave N base (0/64/128/192)

  f32x16 acc[4][2];
  #pragma unroll
  for (int mb = 0; mb < 4; ++mb)
    #pragma unroll
    for (int nb = 0; nb < 2; ++nb)
      #pragma unroll
      for (int r = 0; r < 16; ++r) acc[mb][nb][r] = 0.f;

  // stage one phase-chunk of tile TT: 1 A-chunk + 1 B-chunk per thread
#define S256(TT, PH) do{                                                          \
    const int k0s = (TT) * 32;                                                    \
    unsigned short* dst = &lds[((TT) & 3) * BUFE];                                \
    int lin = (PH) * 512 + tid;                                                   \
    int r_ = lin >> 2, cs_ = lin & 3;                                             \
    int c_ = cs_ ^ (r_ & 3);                                                      \
    int gr_ = m0 + r_; if (gr_ > Mreal - 1) gr_ = Mreal - 1;                      \
    gload16(A + (size_t)gr_ * DIMSZ + k0s + c_ * 8, dst + lin * 8);               \
    gload16(Bm + (size_t)(n0 + r_) * DIMSZ + k0s + c_ * 8, dst + 8192 + lin * 8); \
  } while(0)

  // prologue: tiles 0,1,2 staged (12 loads); retire tile 0 (keep 8 in flight)
  S256(0, 0); S256(0, 1); S256(1, 0); S256(1, 1); S256(2, 0); S256(2, 1);
  asm volatile("s_waitcnt vmcnt(8)" ::: "memory");
  __builtin_amdgcn_s_barrier();

  for (int tt = 0; tt < NT; ++tt){
    const unsigned short* sb = &lds[(tt & 3) * BUFE];
    bf16x8 bfr[2][2], af0[2][2];

    // ---- phase 0: read B (all) + A mb0,1; stage chunk 0 of t+3
    #pragma unroll
    for (int nb = 0; nb < 2; ++nb)
      #pragma unroll
      for (int ks = 0; ks < 2; ++ks){
        int r_ = wcv + nb * 32 + l31;
        int cs_ = (ks * 2 + l5) ^ (r_ & 3);
        bfr[nb][ks] = *(const bf16x8*)(sb + 8192 + r_ * 32 + cs_ * 8);
      }
    #pragma unroll
    for (int mb = 0; mb < 2; ++mb)
      #pragma unroll
      for (int ks = 0; ks < 2; ++ks){
        int r_ = wrv + mb * 32 + l31;
        int cs_ = (ks * 2 + l5) ^ (r_ & 3);
        af0[mb][ks] = *(const bf16x8*)(sb + r_ * 32 + cs_ * 8);
      }
    if (tt < NT - 3) S256(tt + 3, 0);
    __builtin_amdgcn_s_barrier();
    __builtin_amdgcn_s_setprio(1);
    #pragma unroll
    for (int ks = 0; ks < 2; ++ks)
      #pragma unroll
      for (int mb = 0; mb < 2; ++mb)
        #pragma unroll
        for (int nb = 0; nb < 2; ++nb)
          acc[mb][nb] = __builtin_amdgcn_mfma_f32_32x32x16_bf16(af0[mb][ks],
                            bfr[nb][ks], acc[mb][nb], 0, 0, 0);
    __builtin_amdgcn_s_setprio(0);
    __builtin_amdgcn_s_barrier();

    // ---- phase 1: read A mb2,3 (B reused from regs); stage chunk 1 of t+3
    bf16x8 af1[2][2];
    #pragma unroll
    for (int mb = 0; mb < 2; ++mb)
      #pragma unroll
      for (int ks = 0; ks < 2; ++ks){
        int r_ = wrv + 64 + mb * 32 + l31;
        int cs_ = (ks * 2 + l5) ^ (r_ & 3);
        af1[mb][ks] = *(const bf16x8*)(sb + r_ * 32 + cs_ * 8);
      }
    if (tt < NT - 3) S256(tt + 3, 1);
    __builtin_amdgcn_s_barrier();
    __builtin_amdgcn_s_setprio(1);
    #pragma unroll
    for (int ks = 0; ks < 2; ++ks)
      #pragma unroll
      for (int mb = 0; mb < 2; ++mb)
        #pragma unroll
        for (int nb = 0; nb < 2; ++nb)
          acc[2 + mb][nb] = __builtin_amdgcn_mfma_f32_32x32x16_bf16(af1[mb][ks],
                                bfr[nb][ks], acc[2 + mb][nb], 0, 0, 0);
    __builtin_amdgcn_s_setprio(0);
    // tile-end: retire tile tt+1's loads (counted, never 0 until the tail)
    if (tt < NT - 3)       asm volatile("s_waitcnt vmcnt(8)" ::: "memory");
    else if (tt == NT - 3) asm volatile("s_waitcnt vmcnt(4)" ::: "memory");
    else if (tt == NT - 2) asm volatile("s_waitcnt vmcnt(0)" ::: "memory");
    __builtin_amdgcn_s_barrier();
  }
#undef S256

  // epilogue: 32x32 C/D layout col=lane&31, row=(reg&3)+8*(reg>>2)+4*(lane>>5)
  #pragma unroll
  for (int nb = 0; nb < 2; ++nb){
    int col = n0 + wcv + nb * 32 + l31;
    float bz = bias[col];
    #pragma unroll
    for (int mb = 0; mb < 4; ++mb){
      #pragma unroll
      for (int r = 0; r < 16; ++r){
        int row = m0 + wrv + mb * 32 + (r & 3) + 8 * (r >> 2) + 4 * l5;
        if (row < Mreal) C[(size_t)row * DIMSZ + col] = acc[mb][nb][r] + bz;
      }
    }
  }
}

// ---------------- 32x32-MFMA GEMM (O-proj): 128x128 tile, 3 blocks/CU ---------------
__launch_bounds__(256, 3)
__global__ void k_g32(const unsigned short* __restrict__ A,
                      const unsigned short* __restrict__ B0,
                      const unsigned short* __restrict__ B1,
                      const unsigned short* __restrict__ B2,
                      const float* __restrict__ bias0,
                      const float* __restrict__ bias1,
                      const float* __restrict__ bias2,
                      float* __restrict__ C0, float* __restrict__ C1, float* __restrict__ C2,
                      int Mreal)
{
  constexpr int BUFE = 8192;
  constexpr int NT   = DIMSZ / 32;
  __shared__ unsigned short lds[3 * BUFE];

  const unsigned short* Bm = (blockIdx.z == 0) ? B0 : ((blockIdx.z == 1) ? B1 : B2);
  const float* bias        = (blockIdx.z == 0) ? bias0 : ((blockIdx.z == 1) ? bias1 : bias2);
  float* C                 = (blockIdx.z == 0) ? C0 : ((blockIdx.z == 1) ? C1 : C2);

  const int fid = blockIdx.x + gridDim.x * blockIdx.y;
  const int q   = (gridDim.x * gridDim.y) >> 3;
  const int nf  = (fid & 7) * q + (fid >> 3);
  const int m0  = (nf >> 4) * 128, n0 = (nf & 15) * 128;

  const int tid = threadIdx.x;
  const int w = tid >> 6, l = tid & 63;
  const int l31 = l & 31, l5 = l >> 5;
  const int wr = (w >> 1) * 64, wc = (w & 1) * 64;

  f32x16 acc[2][2];
  #pragma unroll
  for (int mb = 0; mb < 2; ++mb)
    #pragma unroll
    for (int nb = 0; nb < 2; ++nb)
      #pragma unroll
      for (int r = 0; r < 16; ++r) acc[mb][nb][r] = 0.f;

#define G32_STAGE(TT, BASE) do{                                                   \
    const int k0s = (TT) * 32;                                                    \
    unsigned short* dst = (BASE);                                                 \
    _Pragma("unroll")                                                             \
    for (int i_ = 0; i_ < 2; ++i_){                                               \
      int lin = i_ * 256 + tid;                                                   \
      int r_ = lin >> 2, pos_ = lin & 3;                                          \
      int gr_ = m0 + r_; if (gr_ > Mreal - 1) gr_ = Mreal - 1;                    \
      gload16(A + (size_t)gr_ * DIMSZ + k0s + (pos_ ^ ((r_ >> 1) & 3)) * 8,       \
              dst + lin * 8);                                                     \
    }                                                                             \
    _Pragma("unroll")                                                             \
    for (int i_ = 0; i_ < 2; ++i_){                                               \
      int lin = i_ * 256 + tid;                                                   \
      int r_ = lin >> 2, pos_ = lin & 3;                                          \
      gload16(Bm + (size_t)(n0 + r_) * DIMSZ + k0s + (pos_ ^ ((r_ >> 1) & 3)) * 8,\
              dst + 4096 + lin * 8);                                              \
    }                                                                             \
  } while(0)

#define G32_COMPUTE(BASE) do{                                                     \
    const unsigned short* sb = (BASE);                                            \
    bf16x8 a_[2][2], b_[2][2];                                                    \
    _Pragma("unroll")                                                             \
    for (int mb = 0; mb < 2; ++mb)                                                \
      _Pragma("unroll")                                                           \
      for (int ks = 0; ks < 2; ++ks){                                             \
        int r_ = wr + mb * 32 + l31;                                              \
        int c_ = (ks * 2 + l5) ^ ((r_ >> 1) & 3);                                 \
        a_[mb][ks] = *(const bf16x8*)(sb + r_ * 32 + c_ * 8);                     \
      }                                                                           \
    _Pragma("unroll")                                                             \
    for (int nb = 0; nb < 2; ++nb)                                                \
      _Pragma("unroll")                                                           \
      for (int ks = 0; ks < 2; ++ks){                                             \
        int r_ = wc + nb * 32 + l31;                                              \
        int c_ = (ks * 2 + l5) ^ ((r_ >> 1) & 3);                                 \
        b_[nb][ks] = *(const bf16x8*)(sb + 4096 + r_ * 32 + c_ * 8);              \
      }                                                                           \
    __builtin_amdgcn_s_setprio(1);                                                \
    _Pragma("unroll")                                                             \
    for (int ks = 0; ks < 2; ++ks)                                                \
      _Pragma("unroll")                                                           \
      for (int mb = 0; mb < 2; ++mb)                                              \
        _Pragma("unroll")                                                         \
        for (int nb = 0; nb < 2; ++nb)                                            \
          acc[mb][nb] = __builtin_amdgcn_mfma_f32_32x32x16_bf16(a_[mb][ks],       \
                            b_[nb][ks], acc[mb][nb], 0, 0, 0);                    \
    __builtin_amdgcn_s_setprio(0);                                                \
  } while(0)

  G32_STAGE(0, lds);
  G32_STAGE(1, lds + BUFE);
  int bc = 0, bs = 2;
  for (int tt = 0; tt < NT - 2; ++tt){
    waitbar<4>();
    G32_STAGE(tt + 2, lds + bs * BUFE);
    G32_COMPUTE(lds + bc * BUFE);
    bs = (bs == 2) ? 0 : bs + 1;
    bc = (bc == 2) ? 0 : bc + 1;
  }
  waitbar<4>();
  G32_COMPUTE(lds + bc * BUFE);
  bc = (bc == 2) ? 0 : bc + 1;
  waitbar<0>();
  G32_COMPUTE(lds + bc * BUFE);

#undef G32_STAGE
#undef G32_COMPUTE

  #pragma unroll
  for (int nb = 0; nb < 2; ++nb){
    int col = n0 + wc + nb * 32 + l31;
    float bz = bias[col];
    #pragma unroll
    for (int mb = 0; mb < 2; ++mb){
      #pragma unroll
      for (int r = 0; r < 16; ++r){
        int row = m0 + wr + mb * 32 + (r & 3) + 8 * (r >> 2) + 4 * l5;
        if (row < Mreal) C[(size_t)row * DIMSZ + col] = acc[mb][nb][r] + bz;
      }
    }
  }
}

// ---------------- fused RMSNorm + RoPE (Q and K in one launch via blockIdx.y) -------
__launch_bounds__(256)
__global__ void k_normrope2(const float* __restrict__ Qf, const float* __restrict__ Kf,
                            const float* __restrict__ nqw, const float* __restrict__ nkw,
                            const float* __restrict__ fc, const float* __restrict__ fs,
                            unsigned short* __restrict__ OutQ, unsigned short* __restrict__ OutK)
{
  const int s = blockIdx.x;
  const int isK = blockIdx.y;
  const float* Xf = isK ? Kf : Qf;
  const float* nw = isK ? nkw : nqw;
  unsigned short* Out = isK ? OutK : OutQ;
  const float scale = isK ? 1.0f : 0.08838834764831843f;
  const int swz = isK;

  const int t = threadIdx.x;
  const int w = t >> 6, l = t & 63;
  __shared__ float wred[4];
  float v[8];
  float ss = 0.f;
  if (s < S_REAL){
    const float4* p = (const float4*)(Xf + (size_t)s * DIMSZ) + t * 2;
    float4 a = p[0], b = p[1];
    v[0]=a.x; v[1]=a.y; v[2]=a.z; v[3]=a.w; v[4]=b.x; v[5]=b.y; v[6]=b.z; v[7]=b.w;
    #pragma unroll
    for (int j = 0; j < 8; ++j) ss += v[j] * v[j];
  }
  #pragma unroll
  for (int off = 32; off >= 1; off >>= 1) ss += __shfl_xor(ss, off);
  if (l == 0) wred[w] = ss;
  __syncthreads();
  float tot = wred[0] + wred[1] + wred[2] + wred[3];
  float rinv = rsqrtf(tot * (1.f / DIMSZ) + 1e-6f);

  const int h  = t >> 4;
  const int d0 = (t & 15) * 8;
  const int b  = t & 15;
  const int bsw = swz ? (b ^ (s & 7)) : b;
  unsigned short* dst = Out + ((size_t)h * S_PAD + s) * DHD + bsw * 8;
  u16x8 o;
  if (s < S_REAL){
    #pragma unroll
    for (int i = 0; i < 4; ++i){
      float c_ = fc[s * DHD + d0 + 2 * i];
      float s_ = fs[s * DHD + d0 + 2 * i + 1];
      float x1 = v[2 * i]     * rinv * nw[t * 8 + 2 * i];
      float x2 = v[2 * i + 1] * rinv * nw[t * 8 + 2 * i + 1];
      o[2 * i]     = f2bf((x1 * c_ - x2 * s_) * scale);
      o[2 * i + 1] = f2bf((x1 * s_ + x2 * c_) * scale);
    }
  } else {
    #pragma unroll
    for (int j = 0; j < 8; ++j) o[j] = 0;
  }
  *(u16x8*)dst = o;
}

// ---------------- V transpose: fp32 [s][2048] -> bf16 [c=h*128+d][s_pad], swizzled ----
__launch_bounds__(256)
__global__ void k_vtrans(const float* __restrict__ Vf, unsigned short* __restrict__ Vth)
{
  __shared__ unsigned short tile[64][72];
  const int t = threadIdx.x;
  const int s0 = blockIdx.x * 64, c0 = blockIdx.y * 64;
  #pragma unroll
  for (int i = 0; i < 4; ++i){
    int r = (t >> 4) * 4 + i;
    int s = s0 + r;
    int cq = (t & 15) * 4;
    float4 val = {0.f, 0.f, 0.f, 0.f};
    if (s < S_REAL) val = *((const float4*)(Vf + (size_t)s * DIMSZ + c0) + (t & 15));
    tile[r][cq + 0] = f2bf(val.x);
    tile[r][cq + 1] = f2bf(val.y);
    tile[r][cq + 2] = f2bf(val.z);
    tile[r][cq + 3] = f2bf(val.w);
  }
  __syncthreads();
  const int cl = t >> 2;
  const int cc = c0 + cl;
  #pragma unroll
  for (int bi = 0; bi < 2; ++bi){
    int b = (t & 3) * 2 + bi;
    u16x8 o;
    #pragma unroll
    for (int j = 0; j < 8; ++j) o[j] = tile[b * 8 + j][cl];
    int bsw = b ^ (cc & 7);
    *(u16x8*)(Vth + (size_t)cc * S_PAD + s0 + bsw * 8) = o;
  }
}

// ---------------- flash attention: swapped-QK^T, 2-phase pipelined ----------------
__launch_bounds__(256)
__global__ void k_attn(const unsigned short* __restrict__ Qh,
                       const unsigned short* __restrict__ Kh,
                       const unsigned short* __restrict__ Vth,
                       unsigned short* __restrict__ O)
{
  __shared__ unsigned short kbuf[2][64 * 128];
  __shared__ unsigned short vbuf[2][128 * 64];
  __shared__ unsigned short pbuf[4][16 * 64];
  const int h = blockIdx.y;
  const int q0 = blockIdx.x * 64;
  const int t = threadIdx.x, w = t >> 6, l = t & 63;
  const int lr = l & 15, lg = l >> 4;

  const unsigned short* Qp = Qh + ((size_t)h * S_PAD + q0 + w * 16 + lr) * DHD;
  bf16x8 qf[4];
  #pragma unroll
  for (int ks = 0; ks < 4; ++ks) qf[ks] = *(const bf16x8*)(Qp + ks * 32 + lg * 8);

  f32x4 acc[8];
  #pragma unroll
  for (int nf = 0; nf < 8; ++nf) acc[nf] = (f32x4){0.f, 0.f, 0.f, 0.f};
  float m = -3.0e38f, lsum = 0.f;

#define ATT_STAGE(KT, BI) do{                                                       \
    _Pragma("unroll")                                                               \
    for (int i_ = 0; i_ < 4; ++i_){                                                 \
      int rK = (w * 4 + i_) * 4 + (l >> 4);                                         \
      gload16(Kh + ((size_t)h * S_PAD + (KT) * 64 + rK) * DHD + (l & 15) * 8,       \
              &kbuf[BI][(w * 4 + i_) * 512]);                                       \
      int rV = (w * 4 + i_) * 8 + (l >> 3);                                         \
      gload16(Vth + ((size_t)h * DHD + rV) * S_PAD + (KT) * 64 + (l & 7) * 8,       \
              &vbuf[BI][(w * 4 + i_) * 512]);                                       \
    }                                                                               \
  } while(0)

  ATT_STAGE(0, 0);
  __syncthreads();

  for (int kt = 0; kt < S_PAD / 64; ++kt){
    const int bi = kt & 1;
    if (kt < S_PAD / 64 - 1) ATT_STAGE(kt + 1, bi ^ 1);

    f32x4 sf[4];
    __builtin_amdgcn_s_setprio(1);
    #pragma unroll
    for (int kvf = 0; kvf < 4; ++kvf){
      sf[kvf] = (f32x4){0.f, 0.f, 0.f, 0.f};
      int r = kvf * 16 + lr;
      #pragma unroll
      for (int ks = 0; ks < 4; ++ks){
        int blk = (ks * 4 + lg) ^ (r & 7);
        bf16x8 kf = *(const bf16x8*)&kbuf[bi][r * 128 + blk * 8];
        sf[kvf] = __builtin_amdgcn_mfma_f32_16x16x32_bf16(kf, qf[ks], sf[kvf], 0, 0, 0);
      }
    }
    __builtin_amdgcn_s_setprio(0);

    float pmax = sf[0][0];
    #pragma unroll
    for (int kvf = 0; kvf < 4; ++kvf)
      #pragma unroll
      for (int j = 0; j < 4; ++j) pmax = fmaxf(pmax, sf[kvf][j]);
    pmax = fmaxf(pmax, __shfl_xor(pmax, 16));
    pmax = fmaxf(pmax, __shfl_xor(pmax, 32));
    float mn = fmaxf(m, pmax);
    float fr = __expf(m - mn);
    m = mn;
    float p[4][4];
    float psum = 0.f;
    #pragma unroll
    for (int kvf = 0; kvf < 4; ++kvf)
      #pragma unroll
      for (int j = 0; j < 4; ++j){ p[kvf][j] = __expf(sf[kvf][j] - mn); psum += p[kvf][j]; }
    lsum = lsum * fr + psum;

    float fv0 = __shfl(fr, lg * 4 + 0);
    float fv1 = __shfl(fr, lg * 4 + 1);
    float fv2 = __shfl(fr, lg * 4 + 2);
    float fv3 = __shfl(fr, lg * 4 + 3);
    f32x4 fv = (f32x4){fv0, fv1, fv2, fv3};
    #pragma unroll
    for (int nf = 0; nf < 8; ++nf) acc[nf] *= fv;

    char* pb = (char*)pbuf[w];
    #pragma unroll
    for (int kvf = 0; kvf < 4; ++kvf){
      uint2 wv;
      wv.x = (uint32_t)f2bf(p[kvf][0]) | ((uint32_t)f2bf(p[kvf][1]) << 16);
      wv.y = (uint32_t)f2bf(p[kvf][2]) | ((uint32_t)f2bf(p[kvf][3]) << 16);
      int byte = lr * 128 + (((kvf * 2 + (lg >> 1)) ^ (lr & 7)) * 16) + (lg & 1) * 8;
      *(uint2*)(pb + byte) = wv;
    }
    bf16x8 pf[2];
    #pragma unroll
    for (int c = 0; c < 2; ++c)
      pf[c] = *(const bf16x8*)(pb + lr * 128 + ((c * 4 + lg) ^ (lr & 7)) * 16);

    __builtin_amdgcn_s_setprio(1);
    #pragma unroll
    for (int nf = 0; nf < 8; ++nf){
      int cc = nf * 16 + lr;
      #pragma unroll
      for (int ks = 0; ks < 2; ++ks){
        int blk = (ks * 4 + lg) ^ (cc & 7);
        bf16x8 vf = *(const bf16x8*)&vbuf[bi][cc * 64 + blk * 8];
        acc[nf] = __builtin_amdgcn_mfma_f32_16x16x32_bf16(pf[ks], vf, acc[nf], 0, 0, 0);
      }
    }
    __builtin_amdgcn_s_setprio(0);

    __syncthreads();
  }
#undef ATT_STAGE

  lsum += __shfl_xor(lsum, 16);
  lsum += __shfl_xor(lsum, 32);
  float ls0 = __shfl(lsum, lg * 4 + 0);
  float ls1 = __shfl(lsum, lg * 4 + 1);
  float ls2 = __shfl(lsum, lg * 4 + 2);
  float ls3 = __shfl(lsum, lg * 4 + 3);
  f32x4 lsv = (f32x4){1.f / ls0, 1.f / ls1, 1.f / ls2, 1.f / ls3};

  #pragma unroll
  for (int nf = 0; nf < 8; ++nf){
    #pragma unroll
    for (int j = 0; j < 4; ++j){
      int row = q0 + w * 16 + lg * 4 + j;
      if (row < S_REAL)
        O[(size_t)row * DIMSZ + h * DHD + nf * 16 + lr] = f2bf(acc[nf][j] * lsv[j]);
    }
  }
}

extern "C" void kernel_launch(void* const* d_in, const int* in_sizes, int n_in,
                              void* d_out, int out_size, void* d_ws, size_t ws_size,
                              hipStream_t stream)
{
  const float* hidden = (const float*)d_in[0];
  const float* fc  = (const float*)d_in[1];
  const float* fs  = (const float*)d_in[2];
  const float* wq  = (const float*)d_in[3];
  const float* bq  = (const float*)d_in[4];
  const float* wk  = (const float*)d_in[5];
  const float* bk  = (const float*)d_in[6];
  const float* wv  = (const float*)d_in[7];
  const float* bv  = (const float*)d_in[8];
  const float* nqw = (const float*)d_in[9];
  const float* nkw = (const float*)d_in[10];
  const float* wo  = (const float*)d_in[11];
  const float* bo  = (const float*)d_in[12];
  float* out = (float*)d_out;

  char* ws = (char*)d_ws;
  size_t off = 0;
  auto alloc = [&](size_t bytes) -> void* {
    void* p = ws + off;
    off += (bytes + 255) & ~(size_t)255;
    return p;
  };
  unsigned short* Xb  = (unsigned short*)alloc((size_t)S_REAL * DIMSZ * 2);
  unsigned short* Wqb = (unsigned short*)alloc((size_t)DIMSZ * DIMSZ * 2);
  unsigned short* Wkb = (unsigned short*)alloc((size_t)DIMSZ * DIMSZ * 2);
  unsigned short* Wvb = (unsigned short*)alloc((size_t)DIMSZ * DIMSZ * 2);
  unsigned short* Wob = (unsigned short*)alloc((size_t)DIMSZ * DIMSZ * 2);
  float* Qf = (float*)alloc((size_t)S_REAL * DIMSZ * 4);
  float* Kf = (float*)alloc((size_t)S_REAL * DIMSZ * 4);
  float* Vf = (float*)alloc((size_t)S_REAL * DIMSZ * 4);
  unsigned short* Qhh = (unsigned short*)alloc((size_t)NHEAD * S_PAD * DHD * 2);
  unsigned short* Khh = (unsigned short*)alloc((size_t)NHEAD * S_PAD * DHD * 2);
  unsigned short* Vth = (unsigned short*)alloc((size_t)NHEAD * DHD * S_PAD * 2);
  unsigned short* Oa  = (unsigned short*)alloc((size_t)S_REAL * DIMSZ * 2);

  // fused convert: X + wq/wk/wv/wo
  {
    int nX = S_REAL * DIMSZ / 8;
    int nW = DIMSZ * DIMSZ / 8;
    int total = nX + 4 * nW;
    k_cvt5<<<total / 256, 256, 0, stream>>>(hidden, wq, wk, wv, wo,
                                            Xb, Wqb, Wkb, Wvb, Wob, nX, nW);
  }

  // fused QKV projection: 256x256 phase-split kernel, 192 blocks
  k_g256<<<dim3(8, 8, 3), 512, 0, stream>>>(Xb, Wqb, Wkb, Wvb, bq, bk, bv,
                                            Qf, Kf, Vf, S_REAL);

  // fused RMSNorm + RoPE for Q and K
  k_normrope2<<<dim3(S_PAD, 2), 256, 0, stream>>>(Qf, Kf, nqw, nkw, fc, fs, Qhh, Khh);

  k_vtrans<<<dim3(S_PAD / 64, DIMSZ / 64), 256, 0, stream>>>(Vf, Vth);

  k_attn<<<dim3(S_PAD / 64, NHEAD), 256, 0, stream>>>(Qhh, Khh, Vth, Oa);

  // output projection: 128x128 tiles -> 256 blocks
  k_g32<<<dim3(16, 16, 1), 256, 0, stream>>>(Oa, Wob, Wob, Wob, bo, bo, bo,
                                             out, out, out, S_REAL);
}

// Round 7
// 220.689 us; speedup vs baseline: 1.0705x; 1.0705x over previous
//
#include <hip/hip_runtime.h>
#include <cstdint>

#define S_REAL 1992
#define S_PAD  2048
#define DIMSZ  2048
#define NHEAD  16
#define DHD    128

typedef float f32x4 __attribute__((ext_vector_type(4)));
typedef float f32x16 __attribute__((ext_vector_type(16)));
typedef __bf16 bf16x8 __attribute__((ext_vector_type(8)));
typedef unsigned short u16x8 __attribute__((ext_vector_type(8)));

__device__ __forceinline__ unsigned short f2bf(float f){
  uint32_t u = __float_as_uint(f);
  u += 0x7fffu + ((u >> 16) & 1u);
  return (unsigned short)(u >> 16);
}

__device__ __forceinline__ void gload16(const void* g, void* l){
  __builtin_amdgcn_global_load_lds(
      (const __attribute__((address_space(1))) uint32_t*)g,
      (__attribute__((address_space(3))) uint32_t*)l,
      16, 0, 0);
}

template<int N> __device__ __forceinline__ void waitbar(){
  if constexpr (N == 4) asm volatile("s_waitcnt vmcnt(4)\n\ts_barrier" ::: "memory");
  else                  asm volatile("s_waitcnt vmcnt(0)\n\ts_barrier" ::: "memory");
}

// ---------------- fused fp32 -> bf16 convert: X + 4 weights in one launch ----------
__launch_bounds__(256)
__global__ void k_cvt5(const float* __restrict__ s0, const float* __restrict__ s1,
                       const float* __restrict__ s2, const float* __restrict__ s3,
                       const float* __restrict__ s4,
                       unsigned short* __restrict__ d0, unsigned short* __restrict__ d1,
                       unsigned short* __restrict__ d2, unsigned short* __restrict__ d3,
                       unsigned short* __restrict__ d4,
                       int nX, int nW)
{
  int i = blockIdx.x * 256 + threadIdx.x;
  const float* s; unsigned short* d; int j;
  if (i < nX){ s = s0; d = d0; j = i; }
  else {
    int k = i - nX;
    int wsel = k / nW; j = k - wsel * nW;
    s = (wsel == 0) ? s1 : (wsel == 1) ? s2 : (wsel == 2) ? s3 : s4;
    d = (wsel == 0) ? d1 : (wsel == 1) ? d2 : (wsel == 2) ? d3 : d4;
  }
  const float4* sp = (const float4*)s + (size_t)j * 2;
  float4 a = sp[0], b = sp[1];
  u16x8 o;
  o[0]=f2bf(a.x); o[1]=f2bf(a.y); o[2]=f2bf(a.z); o[3]=f2bf(a.w);
  o[4]=f2bf(b.x); o[5]=f2bf(b.y); o[6]=f2bf(b.z); o[7]=f2bf(b.w);
  *((u16x8*)d + j) = o;
}

// ---------------- 32x32-MFMA GEMM: 128x128 tile, 3 blocks/CU (round-5 proven) -------
// z==2 writes bf16 to Cb (V path); else fp32 to C.
__launch_bounds__(256, 3)
__global__ void k_g32(const unsigned short* __restrict__ A,
                      const unsigned short* __restrict__ B0,
                      const unsigned short* __restrict__ B1,
                      const unsigned short* __restrict__ B2,
                      const float* __restrict__ bias0,
                      const float* __restrict__ bias1,
                      const float* __restrict__ bias2,
                      float* __restrict__ C0, float* __restrict__ C1,
                      unsigned short* __restrict__ Cb,
                      int Mreal)
{
  constexpr int BUFE = 8192;
  constexpr int NT   = DIMSZ / 32;
  __shared__ unsigned short lds[3 * BUFE];

  const unsigned short* Bm = (blockIdx.z == 0) ? B0 : ((blockIdx.z == 1) ? B1 : B2);
  const float* bias        = (blockIdx.z == 0) ? bias0 : ((blockIdx.z == 1) ? bias1 : bias2);
  float* C                 = (blockIdx.z == 0) ? C0 : C1;

  const int fid = blockIdx.x + gridDim.x * blockIdx.y;
  const int q   = (gridDim.x * gridDim.y) >> 3;
  const int nf  = (fid & 7) * q + (fid >> 3);
  const int m0  = (nf >> 4) * 128, n0 = (nf & 15) * 128;

  const int tid = threadIdx.x;
  const int w = tid >> 6, l = tid & 63;
  const int l31 = l & 31, l5 = l >> 5;
  const int wr = (w >> 1) * 64, wc = (w & 1) * 64;

  f32x16 acc[2][2];
  #pragma unroll
  for (int mb = 0; mb < 2; ++mb)
    #pragma unroll
    for (int nb = 0; nb < 2; ++nb)
      #pragma unroll
      for (int r = 0; r < 16; ++r) acc[mb][nb][r] = 0.f;

#define G32_STAGE(TT, BASE) do{                                                   \
    const int k0s = (TT) * 32;                                                    \
    unsigned short* dst = (BASE);                                                 \
    _Pragma("unroll")                                                             \
    for (int i_ = 0; i_ < 2; ++i_){                                               \
      int lin = i_ * 256 + tid;                                                   \
      int r_ = lin >> 2, pos_ = lin & 3;                                          \
      int gr_ = m0 + r_; if (gr_ > Mreal - 1) gr_ = Mreal - 1;                    \
      gload16(A + (size_t)gr_ * DIMSZ + k0s + (pos_ ^ ((r_ >> 1) & 3)) * 8,       \
              dst + lin * 8);                                                     \
    }                                                                             \
    _Pragma("unroll")                                                             \
    for (int i_ = 0; i_ < 2; ++i_){                                               \
      int lin = i_ * 256 + tid;                                                   \
      int r_ = lin >> 2, pos_ = lin & 3;                                          \
      gload16(Bm + (size_t)(n0 + r_) * DIMSZ + k0s + (pos_ ^ ((r_ >> 1) & 3)) * 8,\
              dst + 4096 + lin * 8);                                              \
    }                                                                             \
  } while(0)

#define G32_COMPUTE(BASE) do{                                                     \
    const unsigned short* sb = (BASE);                                            \
    bf16x8 a_[2][2], b_[2][2];                                                    \
    _Pragma("unroll")                                                             \
    for (int mb = 0; mb < 2; ++mb)                                                \
      _Pragma("unroll")                                                           \
      for (int ks = 0; ks < 2; ++ks){                                             \
        int r_ = wr + mb * 32 + l31;                                              \
        int c_ = (ks * 2 + l5) ^ ((r_ >> 1) & 3);                                 \
        a_[mb][ks] = *(const bf16x8*)(sb + r_ * 32 + c_ * 8);                     \
      }                                                                           \
    _Pragma("unroll")                                                             \
    for (int nb = 0; nb < 2; ++nb)                                                \
      _Pragma("unroll")                                                           \
      for (int ks = 0; ks < 2; ++ks){                                             \
        int r_ = wc + nb * 32 + l31;                                              \
        int c_ = (ks * 2 + l5) ^ ((r_ >> 1) & 3);                                 \
        b_[nb][ks] = *(const bf16x8*)(sb + 4096 + r_ * 32 + c_ * 8);              \
      }                                                                           \
    __builtin_amdgcn_s_setprio(1);                                                \
    _Pragma("unroll")                                                             \
    for (int ks = 0; ks < 2; ++ks)                                                \
      _Pragma("unroll")                                                           \
      for (int mb = 0; mb < 2; ++mb)                                              \
        _Pragma("unroll")                                                         \
        for (int nb = 0; nb < 2; ++nb)                                            \
          acc[mb][nb] = __builtin_amdgcn_mfma_f32_32x32x16_bf16(a_[mb][ks],       \
                            b_[nb][ks], acc[mb][nb], 0, 0, 0);                    \
    __builtin_amdgcn_s_setprio(0);                                                \
  } while(0)

  G32_STAGE(0, lds);
  G32_STAGE(1, lds + BUFE);
  int bc = 0, bs = 2;
  for (int tt = 0; tt < NT - 2; ++tt){
    waitbar<4>();
    G32_STAGE(tt + 2, lds + bs * BUFE);
    G32_COMPUTE(lds + bc * BUFE);
    bs = (bs == 2) ? 0 : bs + 1;
    bc = (bc == 2) ? 0 : bc + 1;
  }
  waitbar<4>();
  G32_COMPUTE(lds + bc * BUFE);
  bc = (bc == 2) ? 0 : bc + 1;
  waitbar<0>();
  G32_COMPUTE(lds + bc * BUFE);

#undef G32_STAGE
#undef G32_COMPUTE

  // epilogue: 32x32 C/D layout col=lane&31, row=(reg&3)+8*(reg>>2)+4*(lane>>5)
  const bool vout = (blockIdx.z == 2);
  #pragma unroll
  for (int nb = 0; nb < 2; ++nb){
    int col = n0 + wc + nb * 32 + l31;
    float bz = bias[col];
    #pragma unroll
    for (int mb = 0; mb < 2; ++mb){
      #pragma unroll
      for (int r = 0; r < 16; ++r){
        int row = m0 + wr + mb * 32 + (r & 3) + 8 * (r >> 2) + 4 * l5;
        if (row < Mreal){
          if (vout) Cb[(size_t)row * DIMSZ + col] = f2bf(acc[mb][nb][r] + bz);
          else      C[(size_t)row * DIMSZ + col] = acc[mb][nb][r] + bz;
        }
      }
    }
  }
}

// ---------------- fused RMSNorm + RoPE (Q and K in one launch via blockIdx.y) -------
__launch_bounds__(256)
__global__ void k_normrope2(const float* __restrict__ Qf, const float* __restrict__ Kf,
                            const float* __restrict__ nqw, const float* __restrict__ nkw,
                            const float* __restrict__ fc, const float* __restrict__ fs,
                            unsigned short* __restrict__ OutQ, unsigned short* __restrict__ OutK)
{
  const int s = blockIdx.x;
  const int isK = blockIdx.y;
  const float* Xf = isK ? Kf : Qf;
  const float* nw = isK ? nkw : nqw;
  unsigned short* Out = isK ? OutK : OutQ;
  const float scale = isK ? 1.0f : 0.08838834764831843f;
  const int swz = isK;

  const int t = threadIdx.x;
  const int w = t >> 6, l = t & 63;
  __shared__ float wred[4];
  float v[8];
  float ss = 0.f;
  if (s < S_REAL){
    const float4* p = (const float4*)(Xf + (size_t)s * DIMSZ) + t * 2;
    float4 a = p[0], b = p[1];
    v[0]=a.x; v[1]=a.y; v[2]=a.z; v[3]=a.w; v[4]=b.x; v[5]=b.y; v[6]=b.z; v[7]=b.w;
    #pragma unroll
    for (int j = 0; j < 8; ++j) ss += v[j] * v[j];
  }
  #pragma unroll
  for (int off = 32; off >= 1; off >>= 1) ss += __shfl_xor(ss, off);
  if (l == 0) wred[w] = ss;
  __syncthreads();
  float tot = wred[0] + wred[1] + wred[2] + wred[3];
  float rinv = rsqrtf(tot * (1.f / DIMSZ) + 1e-6f);

  const int h  = t >> 4;
  const int d0 = (t & 15) * 8;
  const int b  = t & 15;
  const int bsw = swz ? (b ^ (s & 7)) : b;
  unsigned short* dst = Out + ((size_t)h * S_PAD + s) * DHD + bsw * 8;
  u16x8 o;
  if (s < S_REAL){
    #pragma unroll
    for (int i = 0; i < 4; ++i){
      float c_ = fc[s * DHD + d0 + 2 * i];
      float s_ = fs[s * DHD + d0 + 2 * i + 1];
      float x1 = v[2 * i]     * rinv * nw[t * 8 + 2 * i];
      float x2 = v[2 * i + 1] * rinv * nw[t * 8 + 2 * i + 1];
      o[2 * i]     = f2bf((x1 * c_ - x2 * s_) * scale);
      o[2 * i + 1] = f2bf((x1 * s_ + x2 * c_) * scale);
    }
  } else {
    #pragma unroll
    for (int j = 0; j < 8; ++j) o[j] = 0;
  }
  *(u16x8*)dst = o;
}

// ---------------- V transpose: bf16 [s][2048] -> bf16 [c][s_pad], swizzled ----------
__launch_bounds__(256)
__global__ void k_vtrans(const unsigned short* __restrict__ Vb, unsigned short* __restrict__ Vth)
{
  __shared__ unsigned short tile[64][72];
  const int t = threadIdx.x;
  const int s0 = blockIdx.x * 64, c0 = blockIdx.y * 64;
  #pragma unroll
  for (int i = 0; i < 2; ++i){
    int lin = i * 256 + t;
    int r = lin >> 3, ck = lin & 7;
    u16x8 val = (u16x8){0,0,0,0,0,0,0,0};
    if (s0 + r < S_REAL)
      val = *(const u16x8*)(Vb + (size_t)(s0 + r) * DIMSZ + c0 + ck * 8);
    *(u16x8*)&tile[r][ck * 8] = val;
  }
  __syncthreads();
  const int cl = t >> 2;
  const int cc = c0 + cl;
  #pragma unroll
  for (int bi = 0; bi < 2; ++bi){
    int b = (t & 3) * 2 + bi;
    u16x8 o;
    #pragma unroll
    for (int j = 0; j < 8; ++j) o[j] = tile[b * 8 + j][cl];
    int bsw = b ^ (cc & 7);
    *(u16x8*)(Vth + (size_t)cc * S_PAD + s0 + bsw * 8) = o;
  }
}

// ---------------- flash attention: swapped-QK^T, 2-phase, QBLK=128 x 8 waves -------
__launch_bounds__(512)
__global__ void k_attn(const unsigned short* __restrict__ Qh,
                       const unsigned short* __restrict__ Kh,
                       const unsigned short* __restrict__ Vth,
                       unsigned short* __restrict__ O)
{
  __shared__ unsigned short kbuf[2][64 * 128];   // 16KB each
  __shared__ unsigned short vbuf[2][128 * 64];   // 16KB each
  __shared__ unsigned short pbuf[8][16 * 64];    // per-wave P, swizzled (16KB)
  const int h = blockIdx.y;
  const int q0 = blockIdx.x * 128;
  const int t = threadIdx.x, w = t >> 6, l = t & 63;
  const int lr = l & 15, lg = l >> 4;

  const unsigned short* Qp = Qh + ((size_t)h * S_PAD + q0 + w * 16 + lr) * DHD;
  bf16x8 qf[4];
  #pragma unroll
  for (int ks = 0; ks < 4; ++ks) qf[ks] = *(const bf16x8*)(Qp + ks * 32 + lg * 8);

  f32x4 acc[8];
  #pragma unroll
  for (int nf = 0; nf < 8; ++nf) acc[nf] = (f32x4){0.f, 0.f, 0.f, 0.f};
  float m = -3.0e38f, lsum = 0.f;

#define ATT_STAGE(KT, BI) do{                                                       \
    _Pragma("unroll")                                                               \
    for (int i_ = 0; i_ < 2; ++i_){                                                 \
      int lin = i_ * 512 + t;                                                       \
      int rK = lin >> 4, ckK = lin & 15;                                            \
      gload16(Kh + ((size_t)h * S_PAD + (KT) * 64 + rK) * DHD + ckK * 8,            \
              &kbuf[BI][lin * 8]);                                                  \
    }                                                                               \
    _Pragma("unroll")                                                               \
    for (int i_ = 0; i_ < 2; ++i_){                                                 \
      int lin = i_ * 512 + t;                                                       \
      int rV = lin >> 3, ckV = lin & 7;                                             \
      gload16(Vth + ((size_t)h * DHD + rV) * S_PAD + (KT) * 64 + ckV * 8,           \
              &vbuf[BI][lin * 8]);                                                  \
    }                                                                               \
  } while(0)

  ATT_STAGE(0, 0);
  __syncthreads();

  for (int kt = 0; kt < S_PAD / 64; ++kt){
    const int bi = kt & 1;
    if (kt < S_PAD / 64 - 1) ATT_STAGE(kt + 1, bi ^ 1);

    // S^T = K Q^T : lane holds P[kv=16kvf+4lg+j][q=lr]
    f32x4 sf[4];
    __builtin_amdgcn_s_setprio(1);
    #pragma unroll
    for (int kvf = 0; kvf < 4; ++kvf){
      sf[kvf] = (f32x4){0.f, 0.f, 0.f, 0.f};
      int r = kvf * 16 + lr;
      #pragma unroll
      for (int ks = 0; ks < 4; ++ks){
        int blk = (ks * 4 + lg) ^ (r & 7);
        bf16x8 kf = *(const bf16x8*)&kbuf[bi][r * 128 + blk * 8];
        sf[kvf] = __builtin_amdgcn_mfma_f32_16x16x32_bf16(kf, qf[ks], sf[kvf], 0, 0, 0);
      }
    }
    __builtin_amdgcn_s_setprio(0);

    // online softmax (defer-max: skip rescale when max grew by <= 8)
    float pmax = sf[0][0];
    #pragma unroll
    for (int kvf = 0; kvf < 4; ++kvf)
      #pragma unroll
      for (int j = 0; j < 4; ++j) pmax = fmaxf(pmax, sf[kvf][j]);
    pmax = fmaxf(pmax, __shfl_xor(pmax, 16));
    pmax = fmaxf(pmax, __shfl_xor(pmax, 32));

    float fr = 1.f;
    if (!__all(pmax - m <= 8.0f)){
      float mn = fmaxf(m, pmax);
      fr = __expf(m - mn);
      m = mn;
      float fv0 = __shfl(fr, lg * 4 + 0);
      float fv1 = __shfl(fr, lg * 4 + 1);
      float fv2 = __shfl(fr, lg * 4 + 2);
      float fv3 = __shfl(fr, lg * 4 + 3);
      f32x4 fv = (f32x4){fv0, fv1, fv2, fv3};
      #pragma unroll
      for (int nf = 0; nf < 8; ++nf) acc[nf] *= fv;
    }

    float p[4][4];
    float psum = 0.f;
    #pragma unroll
    for (int kvf = 0; kvf < 4; ++kvf)
      #pragma unroll
      for (int j = 0; j < 4; ++j){ p[kvf][j] = __expf(sf[kvf][j] - m); psum += p[kvf][j]; }
    lsum = lsum * fr + psum;

    // stage P[q=lr][kv] packed bf16 pairs, swizzled 16B blocks (wave-local)
    char* pb = (char*)pbuf[w];
    #pragma unroll
    for (int kvf = 0; kvf < 4; ++kvf){
      uint2 wv;
      wv.x = (uint32_t)f2bf(p[kvf][0]) | ((uint32_t)f2bf(p[kvf][1]) << 16);
      wv.y = (uint32_t)f2bf(p[kvf][2]) | ((uint32_t)f2bf(p[kvf][3]) << 16);
      int byte = lr * 128 + (((kvf * 2 + (lg >> 1)) ^ (lr & 7)) * 16) + (lg & 1) * 8;
      *(uint2*)(pb + byte) = wv;
    }
    bf16x8 pf[2];
    #pragma unroll
    for (int c = 0; c < 2; ++c)
      pf[c] = *(const bf16x8*)(pb + lr * 128 + ((c * 4 + lg) ^ (lr & 7)) * 16);

    // O += P V
    __builtin_amdgcn_s_setprio(1);
    #pragma unroll
    for (int nf = 0; nf < 8; ++nf){
      int cc = nf * 16 + lr;
      #pragma unroll
      for (int ks = 0; ks < 2; ++ks){
        int blk = (ks * 4 + lg) ^ (cc & 7);
        bf16x8 vf = *(const bf16x8*)&vbuf[bi][cc * 64 + blk * 8];
        acc[nf] = __builtin_amdgcn_mfma_f32_16x16x32_bf16(pf[ks], vf, acc[nf], 0, 0, 0);
      }
    }
    __builtin_amdgcn_s_setprio(0);

    __syncthreads();
  }
#undef ATT_STAGE

  lsum += __shfl_xor(lsum, 16);
  lsum += __shfl_xor(lsum, 32);
  float ls0 = __shfl(lsum, lg * 4 + 0);
  float ls1 = __shfl(lsum, lg * 4 + 1);
  float ls2 = __shfl(lsum, lg * 4 + 2);
  float ls3 = __shfl(lsum, lg * 4 + 3);
  f32x4 lsv = (f32x4){1.f / ls0, 1.f / ls1, 1.f / ls2, 1.f / ls3};

  #pragma unroll
  for (int nf = 0; nf < 8; ++nf){
    #pragma unroll
    for (int j = 0; j < 4; ++j){
      int row = q0 + w * 16 + lg * 4 + j;
      if (row < S_REAL)
        O[(size_t)row * DIMSZ + h * DHD + nf * 16 + lr] = f2bf(acc[nf][j] * lsv[j]);
    }
  }
}

extern "C" void kernel_launch(void* const* d_in, const int* in_sizes, int n_in,
                              void* d_out, int out_size, void* d_ws, size_t ws_size,
                              hipStream_t stream)
{
  const float* hidden = (const float*)d_in[0];
  const float* fc  = (const float*)d_in[1];
  const float* fs  = (const float*)d_in[2];
  const float* wq  = (const float*)d_in[3];
  const float* bq  = (const float*)d_in[4];
  const float* wk  = (const float*)d_in[5];
  const float* bk  = (const float*)d_in[6];
  const float* wv  = (const float*)d_in[7];
  const float* bv  = (const float*)d_in[8];
  const float* nqw = (const float*)d_in[9];
  const float* nkw = (const float*)d_in[10];
  const float* wo  = (const float*)d_in[11];
  const float* bo  = (const float*)d_in[12];
  float* out = (float*)d_out;

  char* ws = (char*)d_ws;
  size_t off = 0;
  auto alloc = [&](size_t bytes) -> void* {
    void* p = ws + off;
    off += (bytes + 255) & ~(size_t)255;
    return p;
  };
  unsigned short* Xb  = (unsigned short*)alloc((size_t)S_REAL * DIMSZ * 2);
  unsigned short* Wqb = (unsigned short*)alloc((size_t)DIMSZ * DIMSZ * 2);
  unsigned short* Wkb = (unsigned short*)alloc((size_t)DIMSZ * DIMSZ * 2);
  unsigned short* Wvb = (unsigned short*)alloc((size_t)DIMSZ * DIMSZ * 2);
  unsigned short* Wob = (unsigned short*)alloc((size_t)DIMSZ * DIMSZ * 2);
  float* Qf = (float*)alloc((size_t)S_REAL * DIMSZ * 4);
  float* Kf = (float*)alloc((size_t)S_REAL * DIMSZ * 4);
  unsigned short* Vb  = (unsigned short*)alloc((size_t)S_REAL * DIMSZ * 2);
  unsigned short* Qhh = (unsigned short*)alloc((size_t)NHEAD * S_PAD * DHD * 2);
  unsigned short* Khh = (unsigned short*)alloc((size_t)NHEAD * S_PAD * DHD * 2);
  unsigned short* Vth = (unsigned short*)alloc((size_t)NHEAD * DHD * S_PAD * 2);
  unsigned short* Oa  = (unsigned short*)alloc((size_t)S_REAL * DIMSZ * 2);

  // fused convert: X + wq/wk/wv/wo
  {
    int nX = S_REAL * DIMSZ / 8;
    int nW = DIMSZ * DIMSZ / 8;
    int total = nX + 4 * nW;
    k_cvt5<<<total / 256, 256, 0, stream>>>(hidden, wq, wk, wv, wo,
                                            Xb, Wqb, Wkb, Wvb, Wob, nX, nW);
  }

  // fused QKV projection: Q,K fp32; V bf16 direct
  k_g32<<<dim3(16, 16, 3), 256, 0, stream>>>(Xb, Wqb, Wkb, Wvb, bq, bk, bv,
                                             Qf, Kf, Vb, S_REAL);

  // fused RMSNorm + RoPE for Q and K
  k_normrope2<<<dim3(S_PAD, 2), 256, 0, stream>>>(Qf, Kf, nqw, nkw, fc, fs, Qhh, Khh);

  k_vtrans<<<dim3(S_PAD / 64, DIMSZ / 64), 256, 0, stream>>>(Vb, Vth);

  // attention: QBLK=128, 8 waves, 256 blocks
  k_attn<<<dim3(S_PAD / 128, NHEAD), 512, 0, stream>>>(Qhh, Khh, Vth, Oa);

  // output projection: 128x128 tiles -> 256 blocks
  k_g32<<<dim3(16, 16, 1), 256, 0, stream>>>(Oa, Wob, Wob, Wob, bo, bo, bo,
                                             out, out, nullptr, S_REAL);
}